// Round 5
// baseline (344.550 us; speedup 1.0000x reference)
//
#include <hip/hip_runtime.h>
#include <hip/hip_bf16.h>
#include <cstdint>

typedef __attribute__((ext_vector_type(8))) short bf16x8;
typedef __attribute__((ext_vector_type(4))) float f32x4;

#define NCOL 8192
#define TILE 128

union FragU { uint32_t u[4]; bf16x8 v; uint4 q; };

__device__ __forceinline__ uint16_t f2bf(float f) {
  uint32_t x = __builtin_bit_cast(uint32_t, f);
  x += 0x7fffu + ((x >> 16) & 1u);
  return (uint16_t)(x >> 16);
}

// load 8 consecutive f32, scale, round-to-nearest-even to bf16x8
__device__ __forceinline__ bf16x8 load_frag_f32(const float* __restrict__ p, float s) {
  const float4 a = *(const float4*)p;
  const float4 b = *(const float4*)(p + 4);
  FragU f;
  f.u[0] = (uint32_t)f2bf(a.x * s) | ((uint32_t)f2bf(a.y * s) << 16);
  f.u[1] = (uint32_t)f2bf(a.z * s) | ((uint32_t)f2bf(a.w * s) << 16);
  f.u[2] = (uint32_t)f2bf(b.x * s) | ((uint32_t)f2bf(b.y * s) << 16);
  f.u[3] = (uint32_t)f2bf(b.z * s) | ((uint32_t)f2bf(b.w * s) << 16);
  return f.v;
}

__global__ __launch_bounds__(256, 2) void centerhead_kernel(
    const float* __restrict__ ct,
    const float* __restrict__ shw,
    const float* __restrict__ shb, const float* __restrict__ shg,
    const float* __restrict__ shbeta, const float* __restrict__ shmean,
    const float* __restrict__ shvar,
    const float* __restrict__ w1,
    const float* __restrict__ b1, const float* __restrict__ g1,
    const float* __restrict__ beta1, const float* __restrict__ mean1,
    const float* __restrict__ var1,
    const float* __restrict__ hm_w, const float* __restrict__ hm_b,
    const float* __restrict__ reg_w, const float* __restrict__ reg_b,
    const float* __restrict__ height_w, const float* __restrict__ height_b,
    const float* __restrict__ dim_w, const float* __restrict__ dim_b,
    const float* __restrict__ rot_w, const float* __restrict__ rot_b,
    const float* __restrict__ iou_w, const float* __restrict__ iou_b,
    float* __restrict__ outp)
{
  // LDS:
  //  sm_xz: X packed-pair layout [64 c2-rows][stride 132 dwords] (8448 used),
  //         later aliased by Z0 [0,4608) and Z1 [4608,9216), each [128 n][36 dw]
  //  sm_y : Y transposed [128 n][36 dw] (dword = 2 consecutive channels, bf16 pair)
  __shared__ __align__(16) uint32_t sm_xz[9216];
  __shared__ __align__(16) uint32_t sm_y[4608];
  __shared__ __align__(16) float sm_ofsh[64];
  __shared__ __align__(16) float sm_ofh[384];
  __shared__ __align__(16) float sm_bias[16];

  const int t    = threadIdx.x;
  const int wv   = t >> 6;
  const int lane = t & 63;
  const int l15  = lane & 15;
  const int qd   = lane >> 4;          // quad 0..3
  const int bid  = blockIdx.x;
  const int b    = bid >> 6;           // batch
  const int col0 = (bid & 63) * TILE;  // column tile base
  const int nb   = wv * 32;            // wave's 32-column chunk within tile

  // ---- BN-affine offsets + final bias precompute (scales folded into weights) ----
  if (t < 64) {
    float sc = shg[t] * rsqrtf(shvar[t] + 1e-5f);
    sm_ofsh[t] = (shb[t] - shmean[t]) * sc + shbeta[t];
  }
  for (int i = t; i < 384; i += 256) {
    float sc = g1[i] * rsqrtf(var1[i] + 1e-5f);
    sm_ofh[i] = (b1[i] - mean1[i]) * sc + beta1[i];
  }
  if (t < 16) {
    float v = 0.f;
    if (t < 3)       v = hm_b[t];
    else if (t < 5)  v = reg_b[t - 3];
    else if (t < 6)  v = height_b[t - 5];
    else if (t < 9)  v = dim_b[t - 6];
    else if (t < 11) v = rot_b[t - 9];
    else if (t < 12) v = iou_b[t - 11];
    sm_bias[t] = v;
  }

  // ---- stage X (f32) -> LDS packed-pair bf16 layout:
  //      dword[c2][n] = (bf16(X[2c2][n]), bf16(X[2c2+1][n])) ----
  {
    const int c2g = t >> 4;          // 0..15
    const int n0  = (t & 15) * 8;    // 0..120
    #pragma unroll
    for (int i = 0; i < 4; ++i) {
      const int c2 = i * 16 + c2g;   // 0..63
      const size_t base = ((size_t)(b * 128 + 2 * c2)) * NCOL + col0 + n0;
      const float4 ra0 = *(const float4*)(ct + base);
      const float4 ra1 = *(const float4*)(ct + base + 4);
      const float4 rb0 = *(const float4*)(ct + base + NCOL);
      const float4 rb1 = *(const float4*)(ct + base + NCOL + 4);
      uint32_t d0 = (uint32_t)f2bf(ra0.x) | ((uint32_t)f2bf(rb0.x) << 16);
      uint32_t d1 = (uint32_t)f2bf(ra0.y) | ((uint32_t)f2bf(rb0.y) << 16);
      uint32_t d2 = (uint32_t)f2bf(ra0.z) | ((uint32_t)f2bf(rb0.z) << 16);
      uint32_t d3 = (uint32_t)f2bf(ra0.w) | ((uint32_t)f2bf(rb0.w) << 16);
      uint32_t d4 = (uint32_t)f2bf(ra1.x) | ((uint32_t)f2bf(rb1.x) << 16);
      uint32_t d5 = (uint32_t)f2bf(ra1.y) | ((uint32_t)f2bf(rb1.y) << 16);
      uint32_t d6 = (uint32_t)f2bf(ra1.z) | ((uint32_t)f2bf(rb1.z) << 16);
      uint32_t d7 = (uint32_t)f2bf(ra1.w) | ((uint32_t)f2bf(rb1.w) << 16);
      uint32_t* dst = &sm_xz[c2 * 132 + n0];
      *(uint4*)(dst)     = make_uint4(d0, d1, d2, d3);
      *(uint4*)(dst + 4) = make_uint4(d4, d5, d6, d7);
    }
  }

  // ---- preload shared-conv A-frags, BN scale folded into rows:
  //      A[m][k] = sc[m] * shw[m][k], m = mt*16+l15, k = kc*32+qd*8+j ----
  bf16x8 aw[4][4];
  #pragma unroll
  for (int mt = 0; mt < 4; ++mt) {
    const int row = mt * 16 + l15;
    const float sc = shg[row] * rsqrtf(shvar[row] + 1e-5f);
    #pragma unroll
    for (int kc = 0; kc < 4; ++kc)
      aw[mt][kc] = load_frag_f32(shw + row * 128 + kc * 32 + qd * 8, sc);
  }

  __syncthreads();  // X + params ready

  // ---- stage 1: Y = (sc.*shw) @ X ----
  f32x4 accY[4][2];
  #pragma unroll
  for (int mt = 0; mt < 4; ++mt)
    #pragma unroll
    for (int j = 0; j < 2; ++j)
      accY[mt][j] = (f32x4){0.f, 0.f, 0.f, 0.f};

  #pragma unroll
  for (int kc = 0; kc < 4; ++kc) {
    #pragma unroll
    for (int j = 0; j < 2; ++j) {
      FragU f;
      const int base = (kc * 16 + qd * 4) * 132 + nb + j * 16 + l15;
      f.u[0] = sm_xz[base];
      f.u[1] = sm_xz[base + 132];
      f.u[2] = sm_xz[base + 264];
      f.u[3] = sm_xz[base + 396];
      #pragma unroll
      for (int mt = 0; mt < 4; ++mt)
        accY[mt][j] = __builtin_amdgcn_mfma_f32_16x16x32_bf16(aw[mt][kc], f.v, accY[mt][j], 0, 0, 0);
    }
  }

  // offset + ReLU + pack -> Y_t[n][c] (wave-private rows nb..nb+31)
  #pragma unroll
  for (int mt = 0; mt < 4; ++mt) {
    const int cb = mt * 16 + qd * 4;
    const f32x4 of = *(const f32x4*)&sm_ofsh[cb];
    #pragma unroll
    for (int j = 0; j < 2; ++j) {
      const f32x4 v = accY[mt][j];
      float y0 = fmaxf(v[0] + of[0], 0.f);
      float y1 = fmaxf(v[1] + of[1], 0.f);
      float y2 = fmaxf(v[2] + of[2], 0.f);
      float y3 = fmaxf(v[3] + of[3], 0.f);
      uint2 val;
      val.x = (uint32_t)f2bf(y0) | ((uint32_t)f2bf(y1) << 16);
      val.y = (uint32_t)f2bf(y2) | ((uint32_t)f2bf(y3) << 16);
      const int row = nb + j * 16 + l15;
      *(uint2*)&sm_y[row * 36 + mt * 8 + qd * 2] = val;
    }
  }

  // ---- head weights (double-buffered in regs, BN1 scale folded into W1 rows) ----
  const float* wf_ptr[6] = {hm_w, reg_w, height_w, dim_w, rot_w, iou_w};
  const int rowbase[6] = {0, 3, 5, 6, 9, 11};
  const int couts[6]   = {3, 2, 1, 3, 2, 1};

  bf16x8 a1[2][4][2];
  bf16x8 af[2][2];

  auto load_head = [&](int h, bf16x8 (&a1d)[4][2], bf16x8 (&afd)[2]) {
    #pragma unroll
    for (int mt = 0; mt < 4; ++mt) {
      const int row = mt * 16 + l15;
      const float sc = g1[h * 64 + row] * rsqrtf(var1[h * 64 + row] + 1e-5f);
      #pragma unroll
      for (int kc = 0; kc < 2; ++kc)
        a1d[mt][kc] = load_frag_f32(w1 + (h * 64 + row) * 64 + kc * 32 + qd * 8, sc);
    }
    const int rr = l15 - rowbase[h];
    const bool valid = (rr >= 0) && (rr < couts[h]);
    #pragma unroll
    for (int kc = 0; kc < 2; ++kc) {
      if (valid) {
        afd[kc] = load_frag_f32(wf_ptr[h] + rr * 64 + kc * 32 + qd * 8, 1.0f);
      } else {
        FragU f;
        f.q = make_uint4(0, 0, 0, 0);
        afd[kc] = f.v;
      }
    }
  };

  load_head(0, a1[0], af[0]);

  __syncthreads();  // all stage-1 X reads done; X region may now hold Z

  f32x4 accO[2];
  accO[0] = (f32x4){0.f, 0.f, 0.f, 0.f};
  accO[1] = (f32x4){0.f, 0.f, 0.f, 0.f};

  #pragma unroll
  for (int h = 0; h < 6; ++h) {
    const int cur = h & 1;

    // stage 2: Z = (sc1.*W1[h]) @ Y
    f32x4 accZ[4][2];
    #pragma unroll
    for (int mt = 0; mt < 4; ++mt)
      #pragma unroll
      for (int j = 0; j < 2; ++j)
        accZ[mt][j] = (f32x4){0.f, 0.f, 0.f, 0.f};

    #pragma unroll
    for (int kc = 0; kc < 2; ++kc) {
      #pragma unroll
      for (int j = 0; j < 2; ++j) {
        FragU f;
        f.q = *(const uint4*)&sm_y[(nb + j * 16 + l15) * 36 + kc * 16 + qd * 4];
        #pragma unroll
        for (int mt = 0; mt < 4; ++mt)
          accZ[mt][j] = __builtin_amdgcn_mfma_f32_16x16x32_bf16(a1[cur][mt][kc], f.v, accZ[mt][j], 0, 0, 0);
      }
    }

    if (h < 5) load_head(h + 1, a1[cur ^ 1], af[cur ^ 1]);

    // offset + ReLU + pack -> Z_t (wave-private rows; buffers alias dead X region)
    uint32_t* zb = &sm_xz[cur * 4608];
    #pragma unroll
    for (int mt = 0; mt < 4; ++mt) {
      const int cb = h * 64 + mt * 16 + qd * 4;
      const f32x4 of = *(const f32x4*)&sm_ofh[cb];
      #pragma unroll
      for (int j = 0; j < 2; ++j) {
        const f32x4 v = accZ[mt][j];
        float z0 = fmaxf(v[0] + of[0], 0.f);
        float z1 = fmaxf(v[1] + of[1], 0.f);
        float z2 = fmaxf(v[2] + of[2], 0.f);
        float z3 = fmaxf(v[3] + of[3], 0.f);
        uint2 val;
        val.x = (uint32_t)f2bf(z0) | ((uint32_t)f2bf(z1) << 16);
        val.y = (uint32_t)f2bf(z2) | ((uint32_t)f2bf(z3) << 16);
        const int row = nb + j * 16 + l15;
        *(uint2*)&zb[row * 36 + mt * 8 + qd * 2] = val;
      }
    }

    // stage 3: accO += Wf_pad[h] @ Z  (rows offset by rowbase[h], zero-padded)
    #pragma unroll
    for (int kc = 0; kc < 2; ++kc) {
      #pragma unroll
      for (int j = 0; j < 2; ++j) {
        FragU f;
        f.q = *(const uint4*)&zb[(nb + j * 16 + l15) * 36 + kc * 16 + qd * 4];
        accO[j] = __builtin_amdgcn_mfma_f32_16x16x32_bf16(af[cur][kc], f.v, accO[j], 0, 0, 0);
      }
    }
  }

  // ---- epilogue: bias + store rows 0..11 (FLOAT32 out — reference dtype) ----
  if (qd < 3) {
    const f32x4 bs = *(const f32x4*)&sm_bias[qd * 4];
    #pragma unroll
    for (int j = 0; j < 2; ++j) {
      const int col = col0 + nb + j * 16 + l15;
      #pragma unroll
      for (int r = 0; r < 4; ++r) {
        const int row = qd * 4 + r;
        outp[((size_t)(b * 12 + row)) * NCOL + col] = accO[j][r] + bs[r];
      }
    }
  }
}

extern "C" void kernel_launch(void* const* d_in, const int* in_sizes, int n_in,
                              void* d_out, int out_size, void* d_ws, size_t ws_size,
                              hipStream_t stream) {
  (void)out_size; (void)d_ws; (void)ws_size;
  // d_in confirmed to be in setup_inputs() dict order (round-4 forensics);
  // keep the sorted-order signature fallback as insurance.
  static const int sortedPos[25] = {
      0, 24, 19, 21, 20, 22, 23, 8, 3, 5, 4, 6, 7,
      12, 11, 16, 15, 10, 9, 2, 1, 18, 17, 14, 13};
  const bool sorted_order =
      (n_in == 25) && (in_sizes[1] == 3) && (in_sizes[2] == 192) &&
      (in_sizes[8] == 24576) && (in_sizes[24] == 8192);
  const float* p[25];
  for (int r = 0; r < 25; ++r)
    p[r] = (const float*)d_in[sorted_order ? sortedPos[r] : r];

  dim3 grid(2048), block(256);
  hipLaunchKernelGGL(centerhead_kernel, grid, block, 0, stream,
      p[0], p[1], p[2], p[3], p[4], p[5], p[6],
      p[7], p[8], p[9], p[10], p[11], p[12],
      p[13], p[14], p[15], p[16], p[17], p[18],
      p[19], p[20], p[21], p[22], p[23], p[24],
      (float*)d_out);
}

// Round 6
// 294.678 us; speedup vs baseline: 1.1692x; 1.1692x over previous
//
#include <hip/hip_runtime.h>
#include <hip/hip_bf16.h>
#include <cstdint>

typedef __attribute__((ext_vector_type(8))) short bf16x8;
typedef __attribute__((ext_vector_type(4))) float f32x4;

#define NCOL 8192

// ---- workspace layout ----
// uint16 region (bf16 weights, fragment-ordered):
//   AW  [64 m][4 kc][4 qd][8]              -> 8192 el
//   A1  [6 h][64 m][2 kc][4 qd][8]         -> 24576 el
//   AF  [6 h][16 m][2 kc][4 qd][8] (padded)-> 6144 el
// f32 region (starts at float index 19456):
//   OFSH[64]  OFH[384]  BIAS[16]
#define WS_AW 0
#define WS_A1 8192
#define WS_AF 32768
#define WS_U16_TOTAL 38912
#define WS_OFSH 19456
#define WS_OFH  19520
#define WS_BIAS 19904
#define PREP_TOTAL (WS_U16_TOTAL + 464)

union FragU { uint32_t u[4]; bf16x8 v; uint4 q; };

__device__ __forceinline__ uint16_t f2bf(float f) {
  uint32_t x = __builtin_bit_cast(uint32_t, f);
  x += 0x7fffu + ((x >> 16) & 1u);
  return (uint16_t)(x >> 16);
}
__device__ __forceinline__ uint32_t rne_bits(float f) {
  uint32_t x = __builtin_bit_cast(uint32_t, f);
  return x + 0x7fffu + ((x >> 16) & 1u);
}
// pack (lo, hi) -> dword with bf16(lo) in low16: 2x v_add3 + 1x v_perm
__device__ __forceinline__ uint32_t pack_bf16(float lo, float hi) {
  return __builtin_amdgcn_perm(rne_bits(hi), rne_bits(lo), 0x07060302u);
}

// ---------------- prep: fold BN into weights, convert to bf16, frag layout ----------------
__global__ __launch_bounds__(256) void ch_prep(
    const float* __restrict__ shw, const float* __restrict__ shb,
    const float* __restrict__ shg, const float* __restrict__ shbeta,
    const float* __restrict__ shmean, const float* __restrict__ shvar,
    const float* __restrict__ w1, const float* __restrict__ b1,
    const float* __restrict__ g1, const float* __restrict__ beta1,
    const float* __restrict__ mean1, const float* __restrict__ var1,
    const float* __restrict__ hm_w, const float* __restrict__ hm_b,
    const float* __restrict__ reg_w, const float* __restrict__ reg_b,
    const float* __restrict__ height_w, const float* __restrict__ height_b,
    const float* __restrict__ dim_w, const float* __restrict__ dim_b,
    const float* __restrict__ rot_w, const float* __restrict__ rot_b,
    const float* __restrict__ iou_w, const float* __restrict__ iou_b,
    uint16_t* __restrict__ wsq)
{
  const int e = blockIdx.x * 256 + threadIdx.x;
  if (e >= PREP_TOTAL) return;
  const int rowbase[6] = {0, 3, 5, 6, 9, 11};
  const int couts[6]   = {3, 2, 1, 3, 2, 1};
  const float* wfp[6]  = {hm_w, reg_w, height_w, dim_w, rot_w, iou_w};

  if (e < WS_A1) {                       // AW: e = 128m + 32kc + 8q + i
    const int i = e & 7, q = (e >> 3) & 3, kc = (e >> 5) & 3, m = e >> 7;
    const int k = kc * 32 + q * 8 + i;
    const float sc = shg[m] * rsqrtf(shvar[m] + 1e-5f);
    wsq[e] = f2bf(shw[m * 128 + k] * sc);
  } else if (e < WS_AF) {                // A1: e2 = 4096h + 64m + 32kc + 8q + i
    const int e2 = e - WS_A1;
    const int i = e2 & 7, q = (e2 >> 3) & 3, kc = (e2 >> 5) & 1,
              m = (e2 >> 6) & 63, h = e2 >> 12;
    const int k = kc * 32 + q * 8 + i, row = h * 64 + m;
    const float sc = g1[row] * rsqrtf(var1[row] + 1e-5f);
    wsq[e] = f2bf(w1[row * 64 + k] * sc);
  } else if (e < WS_U16_TOTAL) {         // AF: e2 = 1024h + 64m + 32kc + 8q + i
    const int e2 = e - WS_AF;
    const int i = e2 & 7, q = (e2 >> 3) & 3, kc = (e2 >> 5) & 1,
              m = (e2 >> 6) & 15, h = e2 >> 10;
    const int k = kc * 32 + q * 8 + i, rr = m - rowbase[h];
    const float v = (rr >= 0 && rr < couts[h]) ? wfp[h][rr * 64 + k] : 0.f;
    wsq[e] = f2bf(v);
  } else {                               // f32 params
    const int t2 = e - WS_U16_TOTAL;
    float* wff = (float*)wsq;
    float v = 0.f;
    if (t2 < 64) {
      const float sc = shg[t2] * rsqrtf(shvar[t2] + 1e-5f);
      v = (shb[t2] - shmean[t2]) * sc + shbeta[t2];
    } else if (t2 < 448) {
      const int i = t2 - 64;
      const float sc = g1[i] * rsqrtf(var1[i] + 1e-5f);
      v = (b1[i] - mean1[i]) * sc + beta1[i];
    } else {
      const int i = t2 - 448;
      if (i < 3)       v = hm_b[i];
      else if (i < 5)  v = reg_b[i - 3];
      else if (i < 6)  v = height_b[i - 5];
      else if (i < 9)  v = dim_b[i - 6];
      else if (i < 11) v = rot_b[i - 9];
      else if (i < 12) v = iou_b[i - 11];
    }
    wff[WS_OFSH + t2] = v;
  }
}

// ---------------- main: fused 3-stage, wave-autonomous, zero barriers ----------------
__global__ __launch_bounds__(256, 4) void ch_main(
    const float* __restrict__ ct,
    const uint16_t* __restrict__ wsq,
    const float* __restrict__ wsf,
    float* __restrict__ outp)
{
  // Y and Z: [128 n][36 dw], dword d = bf16 pair (channel 2d, 2d+1); rows wave-private
  __shared__ __align__(16) uint32_t sm_y[4608];
  __shared__ __align__(16) uint32_t sm_z[4608];

  const int t    = threadIdx.x;
  const int wv   = t >> 6;
  const int lane = t & 63;
  const int l15  = lane & 15;
  const int qd   = lane >> 4;
  const int bid  = blockIdx.x;
  const int b    = bid >> 6;
  const int col0 = (bid & 63) * 128;
  const int nb   = wv * 32;

  const float* ctb = ct + (size_t)b * 128 * NCOL;
  const int voff0 = qd * 8 * NCOL + col0 + nb + l15;  // lane-varying part of X addr

  // ---- stage 1: Y = (sc.*shw) @ X ; B-frags straight from global ----
  f32x4 accY[4][2];
  #pragma unroll
  for (int mt = 0; mt < 4; ++mt)
    #pragma unroll
    for (int j = 0; j < 2; ++j)
      accY[mt][j] = (f32x4){0.f, 0.f, 0.f, 0.f};

  #pragma unroll
  for (int kc = 0; kc < 4; ++kc) {
    bf16x8 a[4];
    #pragma unroll
    for (int mt = 0; mt < 4; ++mt) {
      FragU fa;
      fa.q = *(const uint4*)(wsq + WS_AW + ((mt * 16 + l15) * 4 + kc) * 32 + qd * 8);
      a[mt] = fa.v;
    }
    #pragma unroll
    for (int j = 0; j < 2; ++j) {
      FragU f;
      #pragma unroll
      for (int i2 = 0; i2 < 4; ++i2) {
        const size_t off = (size_t)((kc * 32 + 2 * i2) * NCOL) + voff0 + j * 16;
        f.u[i2] = pack_bf16(ctb[off], ctb[off + NCOL]);
      }
      #pragma unroll
      for (int mt = 0; mt < 4; ++mt)
        accY[mt][j] = __builtin_amdgcn_mfma_f32_16x16x32_bf16(a[mt], f.v, accY[mt][j], 0, 0, 0);
    }
  }

  // stage-1 epilogue: offset + ReLU + pack -> Y_t (wave-private rows)
  #pragma unroll
  for (int mt = 0; mt < 4; ++mt) {
    const f32x4 of = *(const f32x4*)(wsf + WS_OFSH + mt * 16 + qd * 4);
    #pragma unroll
    for (int j = 0; j < 2; ++j) {
      const f32x4 v = accY[mt][j];
      const float y0 = fmaxf(v[0] + of[0], 0.f);
      const float y1 = fmaxf(v[1] + of[1], 0.f);
      const float y2 = fmaxf(v[2] + of[2], 0.f);
      const float y3 = fmaxf(v[3] + of[3], 0.f);
      uint2 val;
      val.x = pack_bf16(y0, y1);
      val.y = pack_bf16(y2, y3);
      *(uint2*)&sm_y[(nb + j * 16 + l15) * 36 + mt * 8 + qd * 2] = val;
    }
  }

  // ---- heads ----
  f32x4 accO[2];
  accO[0] = (f32x4){0.f, 0.f, 0.f, 0.f};
  accO[1] = (f32x4){0.f, 0.f, 0.f, 0.f};

  #pragma unroll
  for (int h = 0; h < 6; ++h) {
    // stage 2: Z = (sc1.*W1[h]) @ Y
    f32x4 accZ[4][2];
    #pragma unroll
    for (int mt = 0; mt < 4; ++mt)
      #pragma unroll
      for (int j = 0; j < 2; ++j)
        accZ[mt][j] = (f32x4){0.f, 0.f, 0.f, 0.f};

    #pragma unroll
    for (int kc = 0; kc < 2; ++kc) {
      bf16x8 a[4];
      #pragma unroll
      for (int mt = 0; mt < 4; ++mt) {
        FragU fa;
        fa.q = *(const uint4*)(wsq + WS_A1 + ((h * 64 + mt * 16 + l15) * 2 + kc) * 32 + qd * 8);
        a[mt] = fa.v;
      }
      #pragma unroll
      for (int j = 0; j < 2; ++j) {
        FragU f;
        f.q = *(const uint4*)&sm_y[(nb + j * 16 + l15) * 36 + kc * 16 + qd * 4];
        #pragma unroll
        for (int mt = 0; mt < 4; ++mt)
          accZ[mt][j] = __builtin_amdgcn_mfma_f32_16x16x32_bf16(a[mt], f.v, accZ[mt][j], 0, 0, 0);
      }
    }

    // offset + ReLU + pack -> Z_t (wave-private rows; single buffer, same-wave ordering)
    #pragma unroll
    for (int mt = 0; mt < 4; ++mt) {
      const f32x4 of = *(const f32x4*)(wsf + WS_OFH + h * 64 + mt * 16 + qd * 4);
      #pragma unroll
      for (int j = 0; j < 2; ++j) {
        const f32x4 v = accZ[mt][j];
        const float z0 = fmaxf(v[0] + of[0], 0.f);
        const float z1 = fmaxf(v[1] + of[1], 0.f);
        const float z2 = fmaxf(v[2] + of[2], 0.f);
        const float z3 = fmaxf(v[3] + of[3], 0.f);
        uint2 val;
        val.x = pack_bf16(z0, z1);
        val.y = pack_bf16(z2, z3);
        *(uint2*)&sm_z[(nb + j * 16 + l15) * 36 + mt * 8 + qd * 2] = val;
      }
    }

    // stage 3: accO += Wf_pad[h] @ Z
    #pragma unroll
    for (int kc = 0; kc < 2; ++kc) {
      FragU fa;
      fa.q = *(const uint4*)(wsq + WS_AF + ((h * 16 + l15) * 2 + kc) * 32 + qd * 8);
      #pragma unroll
      for (int j = 0; j < 2; ++j) {
        FragU f;
        f.q = *(const uint4*)&sm_z[(nb + j * 16 + l15) * 36 + kc * 16 + qd * 4];
        accO[j] = __builtin_amdgcn_mfma_f32_16x16x32_bf16(fa.v, f.v, accO[j], 0, 0, 0);
      }
    }
  }

  // ---- epilogue: bias + store rows 0..11 (f32 out) ----
  if (qd < 3) {
    const f32x4 bs = *(const f32x4*)(wsf + WS_BIAS + qd * 4);
    #pragma unroll
    for (int j = 0; j < 2; ++j) {
      const int col = col0 + nb + j * 16 + l15;
      #pragma unroll
      for (int r = 0; r < 4; ++r)
        outp[((size_t)(b * 12 + qd * 4 + r)) * NCOL + col] = accO[j][r] + bs[r];
    }
  }
}

extern "C" void kernel_launch(void* const* d_in, const int* in_sizes, int n_in,
                              void* d_out, int out_size, void* d_ws, size_t ws_size,
                              hipStream_t stream) {
  (void)out_size; (void)ws_size;
  // d_in is in setup_inputs() dict order (round-5 verified); sorted fallback kept.
  static const int sortedPos[25] = {
      0, 24, 19, 21, 20, 22, 23, 8, 3, 5, 4, 6, 7,
      12, 11, 16, 15, 10, 9, 2, 1, 18, 17, 14, 13};
  const bool sorted_order =
      (n_in == 25) && (in_sizes[1] == 3) && (in_sizes[2] == 192) &&
      (in_sizes[8] == 24576) && (in_sizes[24] == 8192);
  const float* p[25];
  for (int r = 0; r < 25; ++r)
    p[r] = (const float*)d_in[sorted_order ? sortedPos[r] : r];

  uint16_t* wsq = (uint16_t*)d_ws;   // needs 79,680 B of d_ws

  hipLaunchKernelGGL(ch_prep, dim3((PREP_TOTAL + 255) / 256), dim3(256), 0, stream,
      p[1], p[2], p[3], p[4], p[5], p[6],
      p[7], p[8], p[9], p[10], p[11], p[12],
      p[13], p[14], p[15], p[16], p[17], p[18],
      p[19], p[20], p[21], p[22], p[23], p[24],
      wsq);

  hipLaunchKernelGGL(ch_main, dim3(2048), dim3(256), 0, stream,
      p[0], (const uint16_t*)wsq, (const float*)wsq, (float*)d_out);
}